// Round 18
// baseline (202.440 us; speedup 1.0000x reference)
//
#include <hip/hip_runtime.h>
#include <hip/hip_bf16.h>
#include <cstdint>
#include <cstddef>

// ---------------- types ----------------
typedef float    f32x4   __attribute__((ext_vector_type(4)));
typedef float    float4v __attribute__((ext_vector_type(4)));
typedef short    short8  __attribute__((ext_vector_type(8)));
typedef __bf16   bf16x8  __attribute__((ext_vector_type(8)));
typedef unsigned short ushort4v __attribute__((ext_vector_type(4)));

// ---------------- problem constants ----------------
constexpr int NB   = 4;       // batch
constexpr int TT   = 2048;    // sequence
constexpr int DD   = 1024;    // model dim (= head dim, single head)
constexpr int MTOT = NB * TT; // 8192 tokens

// ---------------- helpers ----------------
__device__ __forceinline__ unsigned short f2bf(float f) {
  union { float f; uint32_t u; } v; v.f = f;
  uint32_t u = v.u;
  uint32_t r = u + 0x7fffu + ((u >> 16) & 1u); // RNE
  return (unsigned short)(r >> 16);
}
__device__ __forceinline__ float bf2f(unsigned short h) {
  union { uint32_t u; float f; } v; v.u = ((uint32_t)h) << 16;
  return v.f;
}

// ---------------- cvt: x,Wv -> bf16 (coalesced); Wq,Wk -> transposed bf16
//            via LDS tiles; zero rowsum (8192 f32) + tile counters (64 int) --
__global__ void cvt_all(const float* __restrict__ x,  const float* __restrict__ wq,
                        const float* __restrict__ wk, const float* __restrict__ wv,
                        unsigned short* __restrict__ xb,  unsigned short* __restrict__ wvb,
                        unsigned short* __restrict__ wqT, unsigned short* __restrict__ wkT,
                        float* __restrict__ rowsum) {
  const int NX  = (MTOT * DD) / 4;  // 2,097,152
  const int NW  = (DD * DD) / 4;    // 262,144
  const int NCVT = (NX + NW) / 256; // 9216 cvt blocks
  const int t = threadIdx.x;

  if ((int)blockIdx.x < NCVT) {
    int i = blockIdx.x * 256 + t;
    // zero rowsum (2048 float4) + 64 counters (16 more float4-equivalents)
    if (i < MTOT / 4 + 16)
      *(float4v*)(rowsum + (size_t)i * 4) = (float4v){0.f, 0.f, 0.f, 0.f};
    const float* s; unsigned short* d; int off;
    if (i < NX)      { s = x;  d = xb;  off = i; }
    else             { s = wv; d = wvb; off = i - NX; }
    float4v v = *(const float4v*)(s + (size_t)off * 4);
    ushort4v o;
    o[0] = f2bf(v[0]); o[1] = f2bf(v[1]); o[2] = f2bf(v[2]); o[3] = f2bf(v[3]);
    *(ushort4v*)(d + (size_t)off * 4) = o;
    return;
  }

  // transpose blocks: 512 total, 64x64 f32 tile -> bf16 transposed
  __shared__ __align__(16) unsigned short tl[64 * 72];  // 144 B rows
  const int tid2 = blockIdx.x - NCVT;       // 0..511
  const int mat  = tid2 >> 8;               // 0=Wq, 1=Wk
  const int tile = tid2 & 255;
  const int o0 = (tile >> 4) * 64;
  const int i0 = (tile & 15) * 64;
  const float* s = (mat == 0) ? wq : wk;
  unsigned short* d = (mat == 0) ? wqT : wkT;

  #pragma unroll
  for (int it = 0; it < 4; ++it) {
    int row = it * 16 + (t >> 4);           // o-local 0..63
    int fc  = (t & 15) * 4;                 // i-local base
    float4v v = *(const float4v*)(s + (size_t)(o0 + row) * DD + i0 + fc);
    #pragma unroll
    for (int j = 0; j < 4; ++j)
      tl[(fc + j) * 72 + row] = f2bf(v[j]);
  }
  __syncthreads();
  #pragma unroll
  for (int it = 0; it < 2; ++it) {
    int ir = it * 32 + (t >> 3);            // i-local 0..63
    int ch = (t & 7) * 8;                   // o chunk
    short8 v = *(const short8*)(tl + ir * 72 + ch);
    *(short8*)(d + (size_t)(i0 + ir) * DD + o0 + ch) = v;   // coalesced 16B
  }
}

// ============================================================================
// 128x128 / BK=64 / dbuf / vmcnt(8) bt-GEMM core (round-3 proven).
// ============================================================================
__device__ __forceinline__ void stage_tile(const unsigned short* g0, int ld,
                                           unsigned short* lds, int l, int w,
                                           int srcswz) {
  #pragma unroll
  for (int it = 0; it < 4; ++it) {
    const int rbase = ((it << 2) + w) << 3;
    const unsigned short* src =
        g0 + (size_t)(rbase + (l >> 3)) * ld + srcswz;
    __builtin_amdgcn_global_load_lds(
        (const __attribute__((address_space(1))) void*)src,
        (__attribute__((address_space(3))) void*)(lds + rbase * 64),
        16, 0, 0);
  }
}

__device__ __forceinline__ void gemm_core(
    const unsigned short* __restrict__ A, const unsigned short* __restrict__ Bm,
    int lda, int ldb, int kbeg, int kend,
    unsigned short* smem, f32x4 acc[4][4])
{
  const int t = threadIdx.x;
  const int w = t >> 6, l = t & 63;
  const int wr = (w >> 1) * 64, wc = (w & 1) * 64;
  const int lrow = l & 15, lk = (l >> 4) * 8;
  const int swr    = (l & 7) << 3;
  const int srcswz = (((l & 7) ^ (l >> 3)) << 3);

  unsigned short* A0 = smem;
  unsigned short* B0 = smem + 8192;
  unsigned short* A1 = smem + 16384;
  unsigned short* B1 = smem + 24576;

  const int NT = (kend - kbeg) >> 6;

  stage_tile(A + kbeg, lda, A0, l, w, srcswz);
  stage_tile(Bm + kbeg, ldb, B0, l, w, srcswz);

  for (int tt = 0; tt < NT; ++tt) {
    unsigned short* Ac = (tt & 1) ? A1 : A0;
    unsigned short* Bc = (tt & 1) ? B1 : B0;
    if (tt + 1 < NT) {
      unsigned short* An = (tt & 1) ? A0 : A1;
      unsigned short* Bn = (tt & 1) ? B0 : B1;
      const int k1 = kbeg + ((tt + 1) << 6);
      stage_tile(A + k1, lda, An, l, w, srcswz);
      stage_tile(Bm + k1, ldb, Bn, l, w, srcswz);
      asm volatile("s_waitcnt vmcnt(8)" ::: "memory");
    } else {
      asm volatile("s_waitcnt vmcnt(0)" ::: "memory");
    }
    __builtin_amdgcn_s_barrier();
    __builtin_amdgcn_sched_barrier(0);

    #pragma unroll
    for (int kk = 0; kk < 64; kk += 32) {
      bf16x8 av[4], bv[4];
      #pragma unroll
      for (int m = 0; m < 4; ++m)
        av[m] = *(const bf16x8*)(Ac + (wr + m * 16 + lrow) * 64 + ((kk + lk) ^ swr));
      #pragma unroll
      for (int n = 0; n < 4; ++n)
        bv[n] = *(const bf16x8*)(Bc + (wc + n * 16 + lrow) * 64 + ((kk + lk) ^ swr));
      __builtin_amdgcn_s_setprio(1);
      #pragma unroll
      for (int m = 0; m < 4; ++m)
        #pragma unroll
        for (int n = 0; n < 4; ++n)
          acc[m][n] = __builtin_amdgcn_mfma_f32_16x16x32_bf16(av[m], bv[n], acc[m][n], 0, 0, 0);
      __builtin_amdgcn_s_setprio(0);
    }
    __builtin_amdgcn_sched_barrier(0);
    __builtin_amdgcn_s_barrier();
    __builtin_amdgcn_sched_barrier(0);
  }
}

// ---------------- Bmat split-K with decoupled last-block reduction ---------
// 512 blocks: (ks 0..7) x (ti,td 0..7 each). Each writes a bf16 partial of
// slice ks for tile (ti,td); fence; the 8th arriver (atomic counter) sums the
// 8 partials into Bmat. Dispatch-order-safe: no block ever waits.
__global__ __launch_bounds__(256, 2) void m_split(
    const unsigned short* __restrict__ wkT,
    const unsigned short* __restrict__ wqT,
    unsigned short* __restrict__ Bpart,
    unsigned short* __restrict__ Bmat,
    int* __restrict__ cnt)
{
  __shared__ __align__(16) unsigned short smem[32768];
  __shared__ int lastflag;

  const int id   = blockIdx.x;                 // 512 blocks, %8==0
  const int work = (id & 7) * 64 + (id >> 3);
  const int ks   = work >> 6;                  // K-slice 0..7
  const int tile = work & 63;
  const int ti   = tile >> 3;                  // i-tile 0..7
  const int td   = tile & 7;                   // d-tile 0..7

  const unsigned short* A = wkT + (size_t)ti * 128 * DD;
  const unsigned short* B = wqT + (size_t)td * 128 * DD;

  f32x4 acc[4][4];
  #pragma unroll
  for (int m = 0; m < 4; ++m)
    #pragma unroll
    for (int n = 0; n < 4; ++n)
      acc[m][n] = (f32x4){0.f, 0.f, 0.f, 0.f};

  gemm_core(A, B, DD, DD, ks * 128, ks * 128 + 128, smem, acc);

  const int t = threadIdx.x, w = t >> 6, l = t & 63;
  const int wr = (w >> 1) * 64, wc = (w & 1) * 64;

  unsigned short* Ts = smem;  // [128][136]
  #pragma unroll
  for (int m = 0; m < 4; ++m)
    #pragma unroll
    for (int n = 0; n < 4; ++n)
      #pragma unroll
      for (int r = 0; r < 4; ++r) {
        int rr = wr + m * 16 + (l >> 4) * 4 + r;
        int cc = wc + n * 16 + (l & 15);
        Ts[rr * 136 + cc] = f2bf(acc[m][n][r]);
      }
  __syncthreads();

  unsigned short* dst = Bpart + (size_t)ks * DD * DD;
  #pragma unroll
  for (int i = 0; i < 8; ++i) {
    int idx = i * 256 + t;
    int rl  = idx >> 4;
    int c16 = (idx & 15) << 3;
    short8 v = *(const short8*)(Ts + rl * 136 + c16);
    *(short8*)(dst + (size_t)(ti * 128 + rl) * DD + td * 128 + c16) = v;
  }

  // ---- decoupled reduction handoff ----
  __threadfence();                 // device-scope: partial visible everywhere
  __syncthreads();                 // all stores in this block issued+fenced
  if (t == 0) lastflag = (atomicAdd(cnt + tile, 1) == 7) ? 1 : 0;
  __syncthreads();
  if (!lastflag) return;
  __threadfence();                 // acquire side

  // this block is the 8th arriver for (ti,td): sum partials -> Bmat
  for (int g = t; g < 4096; g += 256) {        // 4096 ushort4 groups / tile
    const int r    = g >> 5;                   // row-local 0..127
    const int colg = (g & 31) << 2;            // col-local 0..124
    const size_t off = (size_t)(ti * 128 + r) * DD + td * 128 + colg;
    float s0 = 0.f, s1 = 0.f, s2 = 0.f, s3 = 0.f;
    #pragma unroll
    for (int k = 0; k < 8; ++k) {
      ushort4v p = *(const ushort4v*)(Bpart + (size_t)k * DD * DD + off);
      s0 += bf2f(p[0]); s1 += bf2f(p[1]); s2 += bf2f(p[2]); s3 += bf2f(p[3]);
    }
    ushort4v o;
    o[0] = f2bf(s0); o[1] = f2bf(s1); o[2] = f2bf(s2); o[3] = f2bf(s3);
    *(ushort4v*)(Bmat + off) = o;
  }
}

// ---------------- q' = x*M (via Bmat) and V projection ----------------
__global__ __launch_bounds__(256, 2) void qkv_gemm(
    const unsigned short* __restrict__ xb,
    const unsigned short* __restrict__ Bmat,
    const unsigned short* __restrict__ wvb,
    unsigned short* __restrict__ qpb,
    unsigned short* __restrict__ vtb)
{
  __shared__ __align__(16) unsigned short smem[32768];

  const int id   = blockIdx.x;                  // 1024 blocks, %8==0
  const int work = (id & 7) * 128 + (id >> 3);  // XCD-contiguous chunks
  const int which = work >> 9;                  // 0=q', 1=V
  const int rem   = work & 511;
  const int row0  = (rem >> 3) * 128;           // token tile (64)
  const int col0  = (rem & 7) * 128;            // out-dim tile (8)

  const unsigned short* Bop = (which == 0) ? Bmat : wvb;

  f32x4 acc[4][4];
  #pragma unroll
  for (int m = 0; m < 4; ++m)
    #pragma unroll
    for (int n = 0; n < 4; ++n)
      acc[m][n] = (f32x4){0.f, 0.f, 0.f, 0.f};

  gemm_core(xb + (size_t)row0 * DD, Bop + (size_t)col0 * DD, DD, DD, 0, DD, smem, acc);

  const int t = threadIdx.x, w = t >> 6, l = t & 63;
  const int wr = (w >> 1) * 64, wc = (w & 1) * 64;

  unsigned short* Ts = smem;  // [128][136]
  #pragma unroll
  for (int m = 0; m < 4; ++m)
    #pragma unroll
    for (int n = 0; n < 4; ++n)
      #pragma unroll
      for (int r = 0; r < 4; ++r) {
        int rr = wr + m * 16 + (l >> 4) * 4 + r;   // token-local 0..127
        int cc = wc + n * 16 + (l & 15);           // odim-local  0..127
        unsigned short hv = f2bf(acc[m][n][r]);
        if (which == 1) Ts[cc * 136 + rr] = hv;    // V: transposed
        else            Ts[rr * 136 + cc] = hv;
      }
  __syncthreads();

  if (which == 1) {
    const int bb = row0 >> 11, t0 = row0 & 2047;
    #pragma unroll
    for (int i = 0; i < 8; ++i) {
      int idx = i * 256 + t;
      int ol  = idx >> 4;            // odim-local row 0..127
      int c16 = (idx & 15) << 3;     // token chunk
      short8 v = *(const short8*)(Ts + ol * 136 + c16);
      *(short8*)(vtb + ((size_t)bb * DD + col0 + ol) * TT + t0 + c16) = v;
    }
  } else {
    #pragma unroll
    for (int i = 0; i < 8; ++i) {
      int idx = i * 256 + t;
      int rl  = idx >> 4;            // token-local row 0..127
      int c16 = (idx & 15) << 3;     // odim chunk
      short8 v = *(const short8*)(Ts + rl * 136 + c16);
      *(short8*)(qpb + (size_t)(row0 + rl) * DD + col0 + c16) = v;
    }
  }
}

// ---------------- scores = q'*x^T -> P = exp(s*scale) + row sums ----------
__global__ __launch_bounds__(256, 2) void qk_gemm(
    const unsigned short* __restrict__ qpb,
    const unsigned short* __restrict__ xb,
    unsigned short* __restrict__ Pb,
    float* __restrict__ rowsum)
{
  __shared__ __align__(16) unsigned short smem[32768];

  const int id   = blockIdx.x;                 // 544 blocks, %8==0
  const int work = (id & 7) * 68 + (id >> 3);
  const int b    = work / 136;
  const int i    = work - b * 136;
  int row = (int)((sqrtf(8.0f * (float)i + 1.0f) - 1.0f) * 0.5f);
  while ((row + 1) * (row + 2) / 2 <= i) ++row;
  while (row * (row + 1) / 2 > i) --row;
  const int col  = i - row * (row + 1) / 2;
  const int row0 = row * 128, col0 = col * 128;

  const unsigned short* A = qpb + (size_t)b * TT * DD + (size_t)row0 * DD;
  const unsigned short* K = xb  + (size_t)b * TT * DD + (size_t)col0 * DD;

  f32x4 acc[4][4];
  #pragma unroll
  for (int m = 0; m < 4; ++m)
    #pragma unroll
    for (int n = 0; n < 4; ++n)
      acc[m][n] = (f32x4){0.f, 0.f, 0.f, 0.f};

  gemm_core(A, K, DD, DD, 0, DD, smem, acc);

  const float scale = 0.03125f;  // 1/sqrt(1024)
  const int t = threadIdx.x, w = t >> 6, l = t & 63;
  const int wr = (w >> 1) * 64, wc = (w & 1) * 64;
  unsigned short* Prow = Pb + (size_t)b * TT * TT;
  float* rs = rowsum + b * TT;
  #pragma unroll
  for (int m = 0; m < 4; ++m)
    #pragma unroll
    for (int r = 0; r < 4; ++r) {
      const int grow = row0 + wr + m * 16 + (l >> 4) * 4 + r;
      float part = 0.f;
      #pragma unroll
      for (int n = 0; n < 4; ++n) {
        int gcol = col0 + wc + n * 16 + (l & 15);
        float e  = __expf(acc[m][n][r] * scale);
        float ev = (gcol <= grow) ? e : 0.0f;
        Prow[(size_t)grow * TT + gcol] = f2bf(ev);
        part += ev;
      }
      part += __shfl_xor(part, 1);
      part += __shfl_xor(part, 2);
      part += __shfl_xor(part, 4);
      part += __shfl_xor(part, 8);
      if ((l & 15) == 0) atomicAdd(rs + grow, part);
    }
}

// ---------------- PV: O = (P * V) / rowsum (via vT, bt-GEMM), fp32 out -----
__global__ __launch_bounds__(256, 2) void pv_gemm(
    const unsigned short* __restrict__ Pb,
    const unsigned short* __restrict__ vtb,
    const float* __restrict__ rowsum,
    float* __restrict__ out)
{
  __shared__ __align__(16) unsigned short smem[32768];

  const int id   = blockIdx.x;                 // 512 blocks
  const int work = (id & 7) * 64 + (id >> 3);
  const int b    = work >> 7;
  const int rem  = work & 127;
  const int row0 = (15 - (rem >> 3)) * 128;    // q tile, longest first
  const int col0 = (rem & 7) * 128;            // out-dim tile

  const unsigned short* A  = Pb  + (size_t)b * TT * TT + (size_t)row0 * TT;
  const unsigned short* Bm = vtb + (size_t)b * DD * TT + (size_t)col0 * TT;

  f32x4 acc[4][4];
  #pragma unroll
  for (int m = 0; m < 4; ++m)
    #pragma unroll
    for (int n = 0; n < 4; ++n)
      acc[m][n] = (f32x4){0.f, 0.f, 0.f, 0.f};

  gemm_core(A, Bm, TT, TT, 0, row0 + 128, smem, acc);

  const int t = threadIdx.x, w = t >> 6, l = t & 63;
  const int wr = (w >> 1) * 64, wc = (w & 1) * 64;
  const float* rs = rowsum + b * TT;
  #pragma unroll
  for (int m = 0; m < 4; ++m)
    #pragma unroll
    for (int r = 0; r < 4; ++r) {
      const int grow = row0 + wr + m * 16 + (l >> 4) * 4 + r;
      const float inv = 1.0f / rs[grow];
      #pragma unroll
      for (int n = 0; n < 4; ++n) {
        int gcol = col0 + wc + n * 16 + (l & 15);
        out[((size_t)b * TT + grow) * DD + gcol] = acc[m][n][r] * inv;
      }
    }
}

// ---------------- launch ----------------
extern "C" void kernel_launch(void* const* d_in, const int* in_sizes, int n_in,
                              void* d_out, int out_size, void* d_ws, size_t ws_size,
                              hipStream_t stream) {
  const float* x  = (const float*)d_in[0];
  const float* Wq = (const float*)d_in[1];
  const float* Wk = (const float*)d_in[2];
  const float* Wv = (const float*)d_in[3];
  float* out = (float*)d_out;

  unsigned short* ws  = (unsigned short*)d_ws;
  unsigned short* xb   = ws;                         // 8192*1024 bf16
  unsigned short* wvb  = xb   + (size_t)MTOT * DD;   // 1024*1024 bf16
  unsigned short* wqT  = wvb  + (size_t)DD * DD;     // 1024*1024 bf16 (transposed)
  unsigned short* wkT  = wqT  + (size_t)DD * DD;     // 1024*1024 bf16 (transposed)
  unsigned short* Bmat = wkT  + (size_t)DD * DD;     // 1024*1024 bf16
  unsigned short* qpb  = Bmat + (size_t)DD * DD;     // 8192*1024 bf16 (q' = xM)
  unsigned short* Bpart = qpb;                       // ALIAS: 8 x 1024^2 bf16
                                                     // (dead before qkv writes qpb)
  unsigned short* vtb  = qpb  + (size_t)MTOT * DD;   // 4*1024*2048 bf16 (vT)
  unsigned short* Pb   = vtb  + (size_t)MTOT * DD;   // 4*2048*2048 bf16
  float* rowsum = (float*)(Pb + (size_t)NB * TT * TT);   // 8192 f32
  int*   cnt    = (int*)(rowsum + MTOT);                 // 64 int counters

  {
    const int NX = (MTOT * DD) / 4, NW = (DD * DD) / 4;
    const int NCVT = (NX + NW) / 256;              // 9216
    cvt_all<<<dim3(NCVT + 512), 256, 0, stream>>>(
        x, Wq, Wk, Wv, xb, wvb, wqT, wkT, rowsum);
  }

  m_split<<<dim3(512), 256, 0, stream>>>(wkT, wqT, Bpart, Bmat, cnt);

  qkv_gemm<<<dim3(1024), 256, 0, stream>>>(xb, Bmat, wvb, qpb, vtb);

  qk_gemm<<<dim3(544), 256, 0, stream>>>(qpb, xb, Pb, rowsum);

  pv_gemm<<<dim3(512), 256, 0, stream>>>(Pb, vtb, rowsum, out);
}

// Round 19
// 132.427 us; speedup vs baseline: 1.5287x; 1.5287x over previous
//
#include <hip/hip_runtime.h>
#include <hip/hip_bf16.h>
#include <cstdint>
#include <cstddef>

// ---------------- types ----------------
typedef float    f32x4   __attribute__((ext_vector_type(4)));
typedef float    float4v __attribute__((ext_vector_type(4)));
typedef short    short8  __attribute__((ext_vector_type(8)));
typedef __bf16   bf16x8  __attribute__((ext_vector_type(8)));
typedef unsigned short ushort4v __attribute__((ext_vector_type(4)));

// ---------------- problem constants ----------------
constexpr int NB   = 4;       // batch
constexpr int TT   = 2048;    // sequence
constexpr int DD   = 1024;    // model dim (= head dim, single head)
constexpr int MTOT = NB * TT; // 8192 tokens

// ---------------- helpers ----------------
__device__ __forceinline__ unsigned short f2bf(float f) {
  union { float f; uint32_t u; } v; v.f = f;
  uint32_t u = v.u;
  uint32_t r = u + 0x7fffu + ((u >> 16) & 1u); // RNE
  return (unsigned short)(r >> 16);
}
__device__ __forceinline__ float bf2f(unsigned short h) {
  union { uint32_t u; float f; } v; v.u = ((uint32_t)h) << 16;
  return v.f;
}

// ---------------- cvt: x,Wv -> bf16 (coalesced); Wq,Wk -> transposed bf16
//                  via LDS tiles (coalesced both sides); zero rowsum --------
__global__ void cvt_all(const float* __restrict__ x,  const float* __restrict__ wq,
                        const float* __restrict__ wk, const float* __restrict__ wv,
                        unsigned short* __restrict__ xb,  unsigned short* __restrict__ wvb,
                        unsigned short* __restrict__ wqT, unsigned short* __restrict__ wkT,
                        float* __restrict__ rowsum) {
  const int NX  = (MTOT * DD) / 4;  // 2,097,152
  const int NW  = (DD * DD) / 4;    // 262,144
  const int NCVT = (NX + NW) / 256; // 9216 cvt blocks
  const int t = threadIdx.x;

  if ((int)blockIdx.x < NCVT) {
    int i = blockIdx.x * 256 + t;
    if (i < MTOT / 4)
      *(float4v*)(rowsum + (size_t)i * 4) = (float4v){0.f, 0.f, 0.f, 0.f};
    const float* s; unsigned short* d; int off;
    if (i < NX)      { s = x;  d = xb;  off = i; }
    else             { s = wv; d = wvb; off = i - NX; }
    float4v v = *(const float4v*)(s + (size_t)off * 4);
    ushort4v o;
    o[0] = f2bf(v[0]); o[1] = f2bf(v[1]); o[2] = f2bf(v[2]); o[3] = f2bf(v[3]);
    *(ushort4v*)(d + (size_t)off * 4) = o;
    return;
  }

  // transpose blocks: 512 total, 64x64 f32 tile -> bf16 transposed
  __shared__ __align__(16) unsigned short tl[64 * 72];  // 144 B rows (16B-aligned)
  const int tid2 = blockIdx.x - NCVT;       // 0..511
  const int mat  = tid2 >> 8;               // 0=Wq, 1=Wk
  const int tile = tid2 & 255;
  const int o0 = (tile >> 4) * 64;
  const int i0 = (tile & 15) * 64;
  const float* s = (mat == 0) ? wq : wk;
  unsigned short* d = (mat == 0) ? wqT : wkT;

  #pragma unroll
  for (int it = 0; it < 4; ++it) {
    int row = it * 16 + (t >> 4);           // o-local 0..63
    int fc  = (t & 15) * 4;                 // i-local base
    float4v v = *(const float4v*)(s + (size_t)(o0 + row) * DD + i0 + fc);
    #pragma unroll
    for (int j = 0; j < 4; ++j)
      tl[(fc + j) * 72 + row] = f2bf(v[j]);
  }
  __syncthreads();
  #pragma unroll
  for (int it = 0; it < 2; ++it) {
    int ir = it * 32 + (t >> 3);            // i-local 0..63
    int ch = (t & 7) * 8;                   // o chunk
    short8 v = *(const short8*)(tl + ir * 72 + ch);
    *(short8*)(d + (size_t)(i0 + ir) * DD + o0 + ch) = v;   // coalesced 16B
  }
}

// ---------------- sum 8 bf16 partial slices -> Bmat bf16 ----------------
__global__ void cvt_m(const unsigned short* __restrict__ Bpart,
                      unsigned short* __restrict__ Bmat) {
  int i = blockIdx.x * blockDim.x + threadIdx.x;
  if (i >= (DD * DD) / 4) return;
  float s0 = 0.f, s1 = 0.f, s2 = 0.f, s3 = 0.f;
  #pragma unroll
  for (int ks = 0; ks < 8; ++ks) {
    ushort4v p = *(const ushort4v*)(Bpart + (size_t)ks * DD * DD + (size_t)i * 4);
    s0 += bf2f(p[0]); s1 += bf2f(p[1]); s2 += bf2f(p[2]); s3 += bf2f(p[3]);
  }
  ushort4v o;
  o[0] = f2bf(s0); o[1] = f2bf(s1); o[2] = f2bf(s2); o[3] = f2bf(s3);
  *(ushort4v*)(Bmat + (size_t)i * 4) = o;
}

// ============================================================================
// 128x128 / BK=64 / dbuf / vmcnt(8) bt-GEMM core (round-3 proven).
// ============================================================================
__device__ __forceinline__ void stage_tile(const unsigned short* g0, int ld,
                                           unsigned short* lds, int l, int w,
                                           int srcswz) {
  #pragma unroll
  for (int it = 0; it < 4; ++it) {
    const int rbase = ((it << 2) + w) << 3;
    const unsigned short* src =
        g0 + (size_t)(rbase + (l >> 3)) * ld + srcswz;
    __builtin_amdgcn_global_load_lds(
        (const __attribute__((address_space(1))) void*)src,
        (__attribute__((address_space(3))) void*)(lds + rbase * 64),
        16, 0, 0);
  }
}

__device__ __forceinline__ void gemm_core(
    const unsigned short* __restrict__ A, const unsigned short* __restrict__ Bm,
    int lda, int ldb, int kbeg, int kend,
    unsigned short* smem, f32x4 acc[4][4])
{
  const int t = threadIdx.x;
  const int w = t >> 6, l = t & 63;
  const int wr = (w >> 1) * 64, wc = (w & 1) * 64;
  const int lrow = l & 15, lk = (l >> 4) * 8;
  const int swr    = (l & 7) << 3;
  const int srcswz = (((l & 7) ^ (l >> 3)) << 3);

  unsigned short* A0 = smem;
  unsigned short* B0 = smem + 8192;
  unsigned short* A1 = smem + 16384;
  unsigned short* B1 = smem + 24576;

  const int NT = (kend - kbeg) >> 6;

  stage_tile(A + kbeg, lda, A0, l, w, srcswz);
  stage_tile(Bm + kbeg, ldb, B0, l, w, srcswz);

  for (int tt = 0; tt < NT; ++tt) {
    unsigned short* Ac = (tt & 1) ? A1 : A0;
    unsigned short* Bc = (tt & 1) ? B1 : B0;
    if (tt + 1 < NT) {
      unsigned short* An = (tt & 1) ? A0 : A1;
      unsigned short* Bn = (tt & 1) ? B0 : B1;
      const int k1 = kbeg + ((tt + 1) << 6);
      stage_tile(A + k1, lda, An, l, w, srcswz);
      stage_tile(Bm + k1, ldb, Bn, l, w, srcswz);
      asm volatile("s_waitcnt vmcnt(8)" ::: "memory");
    } else {
      asm volatile("s_waitcnt vmcnt(0)" ::: "memory");
    }
    __builtin_amdgcn_s_barrier();
    __builtin_amdgcn_sched_barrier(0);

    #pragma unroll
    for (int kk = 0; kk < 64; kk += 32) {
      bf16x8 av[4], bv[4];
      #pragma unroll
      for (int m = 0; m < 4; ++m)
        av[m] = *(const bf16x8*)(Ac + (wr + m * 16 + lrow) * 64 + ((kk + lk) ^ swr));
      #pragma unroll
      for (int n = 0; n < 4; ++n)
        bv[n] = *(const bf16x8*)(Bc + (wc + n * 16 + lrow) * 64 + ((kk + lk) ^ swr));
      __builtin_amdgcn_s_setprio(1);
      #pragma unroll
      for (int m = 0; m < 4; ++m)
        #pragma unroll
        for (int n = 0; n < 4; ++n)
          acc[m][n] = __builtin_amdgcn_mfma_f32_16x16x32_bf16(av[m], bv[n], acc[m][n], 0, 0, 0);
      __builtin_amdgcn_s_setprio(0);
    }
    __builtin_amdgcn_sched_barrier(0);
    __builtin_amdgcn_s_barrier();
    __builtin_amdgcn_sched_barrier(0);
  }
}

// ---------------- Bmat partial: slice ks of sum_o Wk[o][i]*Wq[o][d] --------
// A = wkT [i][o], B = wqT [d][o]; K-slice [ks*128, ks*128+128).
// Non-atomic: each slice writes its own bf16 partial (coalesced via LDS).
__global__ __launch_bounds__(256, 2) void m_split(
    const unsigned short* __restrict__ wkT,
    const unsigned short* __restrict__ wqT,
    unsigned short* __restrict__ Bpart)
{
  __shared__ __align__(16) unsigned short smem[32768];

  const int id   = blockIdx.x;                 // 512 blocks, %8==0
  const int work = (id & 7) * 64 + (id >> 3);
  const int ks   = work >> 6;                  // K-slice 0..7
  const int tile = work & 63;
  const int ti   = tile >> 3;                  // i-tile 0..7
  const int td   = tile & 7;                   // d-tile 0..7

  const unsigned short* A = wkT + (size_t)ti * 128 * DD;
  const unsigned short* B = wqT + (size_t)td * 128 * DD;

  f32x4 acc[4][4];
  #pragma unroll
  for (int m = 0; m < 4; ++m)
    #pragma unroll
    for (int n = 0; n < 4; ++n)
      acc[m][n] = (f32x4){0.f, 0.f, 0.f, 0.f};

  gemm_core(A, B, DD, DD, ks * 128, ks * 128 + 128, smem, acc);

  const int t = threadIdx.x, w = t >> 6, l = t & 63;
  const int wr = (w >> 1) * 64, wc = (w & 1) * 64;

  unsigned short* Ts = smem;  // [128][136]
  #pragma unroll
  for (int m = 0; m < 4; ++m)
    #pragma unroll
    for (int n = 0; n < 4; ++n)
      #pragma unroll
      for (int r = 0; r < 4; ++r) {
        int rr = wr + m * 16 + (l >> 4) * 4 + r;
        int cc = wc + n * 16 + (l & 15);
        Ts[rr * 136 + cc] = f2bf(acc[m][n][r]);
      }
  __syncthreads();

  unsigned short* dst = Bpart + (size_t)ks * DD * DD;
  #pragma unroll
  for (int i = 0; i < 8; ++i) {
    int idx = i * 256 + t;
    int rl  = idx >> 4;
    int c16 = (idx & 15) << 3;
    short8 v = *(const short8*)(Ts + rl * 136 + c16);
    *(short8*)(dst + (size_t)(ti * 128 + rl) * DD + td * 128 + c16) = v;
  }
}

// ---------------- q' = x*M (via Bmat) and V projection ----------------
__global__ __launch_bounds__(256, 2) void qkv_gemm(
    const unsigned short* __restrict__ xb,
    const unsigned short* __restrict__ Bmat,
    const unsigned short* __restrict__ wvb,
    unsigned short* __restrict__ qpb,
    unsigned short* __restrict__ vtb)
{
  __shared__ __align__(16) unsigned short smem[32768];

  const int id   = blockIdx.x;                  // 1024 blocks, %8==0
  const int work = (id & 7) * 128 + (id >> 3);  // XCD-contiguous chunks
  const int which = work >> 9;                  // 0=q', 1=V
  const int rem   = work & 511;
  const int row0  = (rem >> 3) * 128;           // token tile (64)
  const int col0  = (rem & 7) * 128;            // out-dim tile (8)

  const unsigned short* Bop = (which == 0) ? Bmat : wvb;

  f32x4 acc[4][4];
  #pragma unroll
  for (int m = 0; m < 4; ++m)
    #pragma unroll
    for (int n = 0; n < 4; ++n)
      acc[m][n] = (f32x4){0.f, 0.f, 0.f, 0.f};

  gemm_core(xb + (size_t)row0 * DD, Bop + (size_t)col0 * DD, DD, DD, 0, DD, smem, acc);

  const int t = threadIdx.x, w = t >> 6, l = t & 63;
  const int wr = (w >> 1) * 64, wc = (w & 1) * 64;

  unsigned short* Ts = smem;  // [128][136]
  #pragma unroll
  for (int m = 0; m < 4; ++m)
    #pragma unroll
    for (int n = 0; n < 4; ++n)
      #pragma unroll
      for (int r = 0; r < 4; ++r) {
        int rr = wr + m * 16 + (l >> 4) * 4 + r;   // token-local 0..127
        int cc = wc + n * 16 + (l & 15);           // odim-local  0..127
        unsigned short hv = f2bf(acc[m][n][r]);
        if (which == 1) Ts[cc * 136 + rr] = hv;    // V: transposed
        else            Ts[rr * 136 + cc] = hv;
      }
  __syncthreads();

  if (which == 1) {
    const int bb = row0 >> 11, t0 = row0 & 2047;
    #pragma unroll
    for (int i = 0; i < 8; ++i) {
      int idx = i * 256 + t;
      int ol  = idx >> 4;            // odim-local row 0..127
      int c16 = (idx & 15) << 3;     // token chunk
      short8 v = *(const short8*)(Ts + ol * 136 + c16);
      *(short8*)(vtb + ((size_t)bb * DD + col0 + ol) * TT + t0 + c16) = v;
    }
  } else {
    #pragma unroll
    for (int i = 0; i < 8; ++i) {
      int idx = i * 256 + t;
      int rl  = idx >> 4;            // token-local row 0..127
      int c16 = (idx & 15) << 3;     // odim chunk
      short8 v = *(const short8*)(Ts + rl * 136 + c16);
      *(short8*)(qpb + (size_t)(row0 + rl) * DD + col0 + c16) = v;
    }
  }
}

// ---------------- scores = q'*x^T -> P = exp(s*scale) + row sums ----------
__global__ __launch_bounds__(256, 2) void qk_gemm(
    const unsigned short* __restrict__ qpb,
    const unsigned short* __restrict__ xb,
    unsigned short* __restrict__ Pb,
    float* __restrict__ rowsum)
{
  __shared__ __align__(16) unsigned short smem[32768];

  const int id   = blockIdx.x;                 // 544 blocks, %8==0
  const int work = (id & 7) * 68 + (id >> 3);
  const int b    = work / 136;
  const int i    = work - b * 136;
  int row = (int)((sqrtf(8.0f * (float)i + 1.0f) - 1.0f) * 0.5f);
  while ((row + 1) * (row + 2) / 2 <= i) ++row;
  while (row * (row + 1) / 2 > i) --row;
  const int col  = i - row * (row + 1) / 2;
  const int row0 = row * 128, col0 = col * 128;

  const unsigned short* A = qpb + (size_t)b * TT * DD + (size_t)row0 * DD;
  const unsigned short* K = xb  + (size_t)b * TT * DD + (size_t)col0 * DD;

  f32x4 acc[4][4];
  #pragma unroll
  for (int m = 0; m < 4; ++m)
    #pragma unroll
    for (int n = 0; n < 4; ++n)
      acc[m][n] = (f32x4){0.f, 0.f, 0.f, 0.f};

  gemm_core(A, K, DD, DD, 0, DD, smem, acc);

  const float scale = 0.03125f;  // 1/sqrt(1024)
  const int t = threadIdx.x, w = t >> 6, l = t & 63;
  const int wr = (w >> 1) * 64, wc = (w & 1) * 64;
  unsigned short* Prow = Pb + (size_t)b * TT * TT;
  float* rs = rowsum + b * TT;
  #pragma unroll
  for (int m = 0; m < 4; ++m)
    #pragma unroll
    for (int r = 0; r < 4; ++r) {
      const int grow = row0 + wr + m * 16 + (l >> 4) * 4 + r;
      float part = 0.f;
      #pragma unroll
      for (int n = 0; n < 4; ++n) {
        int gcol = col0 + wc + n * 16 + (l & 15);
        float e  = __expf(acc[m][n][r] * scale);
        float ev = (gcol <= grow) ? e : 0.0f;
        Prow[(size_t)grow * TT + gcol] = f2bf(ev);
        part += ev;
      }
      part += __shfl_xor(part, 1);
      part += __shfl_xor(part, 2);
      part += __shfl_xor(part, 4);
      part += __shfl_xor(part, 8);
      if ((l & 15) == 0) atomicAdd(rs + grow, part);
    }
}

// ---------------- PV: O = (P * V) / rowsum (via vT, bt-GEMM), fp32 out -----
__global__ __launch_bounds__(256, 2) void pv_gemm(
    const unsigned short* __restrict__ Pb,
    const unsigned short* __restrict__ vtb,
    const float* __restrict__ rowsum,
    float* __restrict__ out)
{
  __shared__ __align__(16) unsigned short smem[32768];

  const int id   = blockIdx.x;                 // 512 blocks
  const int work = (id & 7) * 64 + (id >> 3);
  const int b    = work >> 7;
  const int rem  = work & 127;
  const int row0 = (15 - (rem >> 3)) * 128;    // q tile, longest first
  const int col0 = (rem & 7) * 128;            // out-dim tile

  const unsigned short* A  = Pb  + (size_t)b * TT * TT + (size_t)row0 * TT;
  const unsigned short* Bm = vtb + (size_t)b * DD * TT + (size_t)col0 * TT;

  f32x4 acc[4][4];
  #pragma unroll
  for (int m = 0; m < 4; ++m)
    #pragma unroll
    for (int n = 0; n < 4; ++n)
      acc[m][n] = (f32x4){0.f, 0.f, 0.f, 0.f};

  gemm_core(A, Bm, TT, TT, 0, row0 + 128, smem, acc);

  const int t = threadIdx.x, w = t >> 6, l = t & 63;
  const int wr = (w >> 1) * 64, wc = (w & 1) * 64;
  const float* rs = rowsum + b * TT;
  #pragma unroll
  for (int m = 0; m < 4; ++m)
    #pragma unroll
    for (int r = 0; r < 4; ++r) {
      const int grow = row0 + wr + m * 16 + (l >> 4) * 4 + r;
      const float inv = 1.0f / rs[grow];
      #pragma unroll
      for (int n = 0; n < 4; ++n) {
        int gcol = col0 + wc + n * 16 + (l & 15);
        out[((size_t)b * TT + grow) * DD + gcol] = acc[m][n][r] * inv;
      }
    }
}

// ---------------- launch ----------------
extern "C" void kernel_launch(void* const* d_in, const int* in_sizes, int n_in,
                              void* d_out, int out_size, void* d_ws, size_t ws_size,
                              hipStream_t stream) {
  const float* x  = (const float*)d_in[0];
  const float* Wq = (const float*)d_in[1];
  const float* Wk = (const float*)d_in[2];
  const float* Wv = (const float*)d_in[3];
  float* out = (float*)d_out;

  unsigned short* ws  = (unsigned short*)d_ws;
  unsigned short* xb   = ws;                         // 8192*1024 bf16
  unsigned short* wvb  = xb   + (size_t)MTOT * DD;   // 1024*1024 bf16
  unsigned short* wqT  = wvb  + (size_t)DD * DD;     // 1024*1024 bf16 (transposed)
  unsigned short* wkT  = wqT  + (size_t)DD * DD;     // 1024*1024 bf16 (transposed)
  unsigned short* Bmat = wkT  + (size_t)DD * DD;     // 1024*1024 bf16
  unsigned short* qpb  = Bmat + (size_t)DD * DD;     // 8192*1024 bf16 (q' = xM)
  unsigned short* Bpart = qpb;                       // ALIAS: 8 x 1024^2 bf16
                                                     // (dead before qkv writes qpb)
  unsigned short* vtb  = qpb  + (size_t)MTOT * DD;   // 4*1024*2048 bf16 (vT)
  unsigned short* Pb   = vtb  + (size_t)MTOT * DD;   // 4*2048*2048 bf16
  float* rowsum = (float*)(Pb + (size_t)NB * TT * TT);   // 8192 f32

  {
    const int NX = (MTOT * DD) / 4, NW = (DD * DD) / 4;
    const int NCVT = (NX + NW) / 256;              // 9216
    cvt_all<<<dim3(NCVT + 512), 256, 0, stream>>>(
        x, Wq, Wk, Wv, xb, wvb, wqT, wkT, rowsum);
  }

  m_split<<<dim3(512), 256, 0, stream>>>(wkT, wqT, Bpart);

  cvt_m<<<dim3((DD * DD / 4 + 255) / 256), 256, 0, stream>>>(Bpart, Bmat);

  qkv_gemm<<<dim3(1024), 256, 0, stream>>>(xb, Bmat, wvb, qpb, vtb);

  qk_gemm<<<dim3(544), 256, 0, stream>>>(qpb, xb, Pb, rowsum);

  pv_gemm<<<dim3(512), 256, 0, stream>>>(Pb, vtb, rowsum, out);
}